// Round 1
// 68.864 us; speedup vs baseline: 1.0885x; 1.0885x over previous
//
#include <hip/hip_runtime.h>
#include <math.h>

// DiffractiveLayer: out[j] = sum_i modes[i]*G[i,j]*dA, G[i,j] = f(a-c, b-d)
// -> 2D complex convolution with a 191x191 tap table.
//
// Structure (R4): TWO dispatches only.
//   1. precompute: taps (fp64 geometry + arg-reduced hw sincos) + modes
//      + zero d_out (replaces a separate memset dispatch).
//   2. conv: register-blocked direct convolution out of LDS, 12-way
//      atomicAdd accumulation into d_out.
// R3's single-kernel + device-scope spin-barrier variant measured 241 us:
// cross-XCD coherence storms make grid barriers ~100x the cost of the
// launch gaps they save. Never again on this chip.
//
// R5: inner loop converted from 4x v_fma_f32 per complex MAC to
// 2x v_pk_fma_f32 (op_sel/neg_lo encode the complex operand swizzle,
// zero extra moves, bit-identical FLOP order). Tests whether CDNA4 packed
// fp32 is dual-rate (CDNA2 was; AMD specs are silent for gfx950). Also
// #pragma unroll 6 so the 3-deep tap ring rotates by renaming.
//
// Timed-iteration floor: harness poisons 268 MB of d_ws every iteration
// (~39.5 us at ~85% HBM peak) + graph replay overhead. Our dispatches are
// ~10 us combined.

#define NN 96
#define M (NN*NN)
#define GH 191           // 2N-1 tap rows/cols
#define GWG 192          // global tap row stride (float2)
#define GW2 200          // LDS tap row stride (float2), slack for ring overrun
#define MW2 104          // LDS modes row stride (float2), de-banked

typedef __attribute__((ext_vector_type(4))) float f32x4;
typedef __attribute__((ext_vector_type(2))) float f32x2;

__device__ float2 g_G[GH * GWG];    // tap table, dA folded in
__device__ float2 g_modes[M];       // exp(j*w)*x

__global__ __launch_bounds__(256) void precompute_kernel(
    const float* __restrict__ x, const float* __restrict__ w,
    const float* __restrict__ xc, const float* __restrict__ yc,
    float* __restrict__ out, int out_floats) {
  const double DZ = 1e-5, LAMBDA = 1.55e-6;
  const double TWO_PI     = 6.283185307179586476925;
  const double INV_TWO_PI = 0.15915494309189533577;
  const double K  = TWO_PI / LAMBDA;
  const double DA = LAMBDA * LAMBDA;          // pitch == lambda

  int idx = blockIdx.x * 256 + threadIdx.x;

  if (idx < out_floats) out[idx] = 0.f;       // fused d_out zeroing

  if (idx < GH * GH) {
    int u = idx / GH - (NN - 1);
    int v = idx % GH - (NN - 1);
    // fp32-rounded input coords match the reference's systematic rounding
    double dx = (double)xc[u < 0 ? -u : u] - (double)xc[0];
    double dy = (double)yc[v < 0 ? -v : v] - (double)yc[0];
    double r2 = dx * dx + dy * dy + DZ * DZ;
    double r  = sqrt(r2);
    double invr2 = 1.0 / r2;
    double amp = DZ * DA * invr2;               // dz/r^2 * dA
    double A = amp * INV_TWO_PI * (r * invr2);  // amp/(2*pi*r)
    double B = amp / LAMBDA;
    double ph = K * r;                          // up to ~843 rad
    double nred = rint(ph * INV_TWO_PI);
    float red = (float)fma(-nred, TWO_PI, ph);  // |red| <= pi, err ~1e-13
    float s, cs;
    __sincosf(red, &s, &cs);
    // (A - jB)(cs + js) = (A cs + B s) + j(A s - B cs)
    g_G[(u + NN - 1) * GWG + (v + NN - 1)] =
        make_float2((float)(A * cs + B * s), (float)(A * s - B * cs));
  } else if (idx < GH * GH + M) {
    int i = idx - GH * GH;
    float s, cs;
    sincosf(w[i], &s, &cs);
    float xv = x[i];
    g_modes[i] = make_float2(cs * xv, s * xv);
  }
}

// grid: (96 output rows c, 12 source-row chunks of 8), block 192.
// Thread t: q = t%24 -> outputs d = 4q..4q+3;  h = t/24 -> source row a0+h.
// Register ring of 3 float4 (6 taps) -> 1 new b128 tap read per 2 b-steps.
__global__ __launch_bounds__(192) void conv_kernel(float* __restrict__ out,
                                                   int interleaved) {
  int c  = blockIdx.x;
  int a0 = blockIdx.y * 8;
  int t  = threadIdx.x;

  __shared__ float2 s_modes[8 * MW2];      // 8 rows x 96 (stride 104)
  __shared__ float2 s_G[8 * GW2 + 8];      // 8 rows x 192 (stride 200) + slack
  __shared__ float2 s_red[8 * NN];

  // stage modes: 8 rows x 48 float4, 2 per thread
  #pragma unroll
  for (int k = 0; k < 2; ++k) {
    int idx = k * 192 + t;              // 0..383
    int row = idx / 48, col = idx % 48;
    const float4* src = (const float4*)(g_modes + (a0 + row) * NN);
    ((float4*)(s_modes + row * MW2))[col] = src[col];
  }
  // stage taps: 8 rows x 96 float4, 4 per thread
  #pragma unroll
  for (int k = 0; k < 4; ++k) {
    int idx = k * 192 + t;              // 0..767
    int row = idx / 96, col = idx % 96;
    const float4* src = (const float4*)(g_G + (a0 + row - c + (NN - 1)) * GWG);
    ((float4*)(s_G + row * GW2))[col] = src[col];
  }
  __syncthreads();

  int q = t % 24;
  int h = t / 24;
  int base = 92 - 4 * q;                // even, >= 0
  const f32x4* Grow = (const f32x4*)(s_G + h * GW2);
  const f32x4* Mrow = (const f32x4*)(s_modes + h * MW2);
  int gb = base >> 1;

  f32x4 g0 = Grow[gb];
  f32x4 g1 = Grow[gb + 1];
  f32x4 g2 = Grow[gb + 2];
  f32x2 a0c = {0.f, 0.f}, a1c = {0.f, 0.f}, a2c = {0.f, 0.f}, a3c = {0.f, 0.f};

#define LO2(v4) __builtin_shufflevector(v4, v4, 0, 1)
#define HI2(v4) __builtin_shufflevector(v4, v4, 2, 3)

// Complex MAC  acc += m * g  with m=(mr,mi), g=(gr,gi), all f32x2 pairs.
// inst1: lo: mr*gr + acc.x            hi: mr*gi + acc.y
// inst2: lo: mi*(-gi) + acc.x         hi: mi*gr + acc.y
// -> identical per-component FLOP order to the scalar 4-fma version.
#define CFMA_PK(acc, m2, gg)                                                  \
  asm("v_pk_fma_f32 %0, %1, %2, %0 op_sel:[0,0,0] op_sel_hi:[0,1,1]\n\t"      \
      "v_pk_fma_f32 %0, %1, %2, %0 op_sel:[1,1,0] op_sel_hi:[1,0,1] neg_lo:[0,1,0]" \
      : "+v"(acc) : "v"(m2), "v"(gg))

  #pragma unroll 6
  for (int b = 0; b < NN; b += 2) {
    f32x4 mm = Mrow[b >> 1];   // m[b]=(x,y)  m[b+1]=(z,w)
    f32x2 m01 = LO2(mm), m23 = HI2(mm);
    f32x2 g0a = LO2(g0), g0b = HI2(g0);
    f32x2 g1a = LO2(g1), g1b = HI2(g1);
    f32x2 g2a = LO2(g2);
    CFMA_PK(a0c, m01, g1b);
    CFMA_PK(a0c, m23, g2a);
    CFMA_PK(a1c, m01, g1a);
    CFMA_PK(a1c, m23, g1b);
    CFMA_PK(a2c, m01, g0b);
    CFMA_PK(a2c, m23, g1a);
    CFMA_PK(a3c, m01, g0a);
    CFMA_PK(a3c, m23, g0b);
    g0 = g1;
    g1 = g2;
    g2 = Grow[gb + 3 + (b >> 1)];   // slack covers final overrun
  }
#undef CFMA_PK
#undef LO2
#undef HI2

  int dbase = 4 * q;
  s_red[h * NN + dbase + 0] = make_float2(a0c.x, a0c.y);
  s_red[h * NN + dbase + 1] = make_float2(a1c.x, a1c.y);
  s_red[h * NN + dbase + 2] = make_float2(a2c.x, a2c.y);
  s_red[h * NN + dbase + 3] = make_float2(a3c.x, a3c.y);
  __syncthreads();

  if (t < NN) {
    float re = 0.f, im = 0.f;
    #pragma unroll
    for (int hh = 0; hh < 8; ++hh) {
      re += s_red[hh * NN + t].x;
      im += s_red[hh * NN + t].y;
    }
    int j = c * NN + t;
    if (interleaved) {
      atomicAdd(out + 2 * j,     re);
      atomicAdd(out + 2 * j + 1, im);
    } else {
      atomicAdd(out + j, re);
    }
  }
}

extern "C" void kernel_launch(void* const* d_in, const int* in_sizes, int n_in,
                              void* d_out, int out_size, void* d_ws, size_t ws_size,
                              hipStream_t stream) {
  const float* x  = (const float*)d_in[0];
  const float* w  = (const float*)d_in[1];
  const float* xc = (const float*)d_in[2];
  const float* yc = (const float*)d_in[3];
  float* out = (float*)d_out;

  int interleaved = (out_size >= 2 * M) ? 1 : 0;
  int out_floats  = interleaved ? 2 * M : M;

  int total = GH * GH + M;   // 45697 work items; out_floats < total covered
  precompute_kernel<<<(total + 255) / 256, 256, 0, stream>>>(
      x, w, xc, yc, out, out_floats);

  conv_kernel<<<dim3(NN, 12), 192, 0, stream>>>(out, interleaved);
}